// Round 1
// baseline (188.289 us; speedup 1.0000x reference)
//
#include <hip/hip_runtime.h>

#define VOCAB 50257
#define NTOK 4096
#define P1_THREADS 256
#define P2_THREADS 1024
#define NEG_HUGE -3.402823466e+38f

struct OS { float m1, m2, Z, S1; };

__device__ __forceinline__ void os_init(OS& s) {
  s.m1 = NEG_HUGE; s.m2 = NEG_HUGE; s.Z = 0.0f; s.S1 = 0.0f;
}

// Online update with element x:
//   m1' = max(m1, x); Z' = e^{m1-m1'} Z + e^{x-m1'};
//   S1' = e^{m1-m1'}(S1 + (m1-m1')Z) + (x-m1') e^{x-m1'}
__device__ __forceinline__ void os_update(OS& s, float x) {
  float nm1 = fmaxf(s.m1, x);
  float d   = s.m1 - nm1;     // <= 0
  float dx  = x - nm1;        // <= 0
  float ed  = __expf(d);
  float edx = __expf(dx);
  s.m2 = fmaxf(s.m2, fminf(s.m1, x));
  s.S1 = fmaf(dx, edx, ed * fmaf(d, s.Z, s.S1));
  s.Z  = fmaf(ed, s.Z, edx);
  s.m1 = nm1;
}

__device__ __forceinline__ void os_merge(OS& a, const OS& b) {
  float M   = fmaxf(a.m1, b.m1);
  float m2  = fmaxf(fmaxf(a.m2, b.m2), fminf(a.m1, b.m1));
  float ea  = __expf(a.m1 - M);
  float eb  = __expf(b.m1 - M);
  float S1  = ea * fmaf(a.m1 - M, a.Z, a.S1) + eb * fmaf(b.m1 - M, b.Z, b.S1);
  float Z   = fmaf(ea, a.Z, eb * b.Z);
  a.m1 = M; a.m2 = m2; a.Z = Z; a.S1 = S1;
}

__global__ __launch_bounds__(P1_THREADS) void cggr_rowstats(
    const float* __restrict__ logits, const int* __restrict__ targets,
    float* __restrict__ diff, float* __restrict__ loss, float* __restrict__ conf)
{
  const int row = blockIdx.x;
  const float* __restrict__ x = logits + (size_t)row * VOCAB;
  const int tid = threadIdx.x;

  float xt = 0.0f;
  if (tid == 0) {
    int t = targets[row];
    xt = x[t];
  }

  OS s0, s1, s2, s3;
  os_init(s0); os_init(s1); os_init(s2); os_init(s3);

  // Rows are not 16B-aligned (VOCAB odd): peel head so float4 region is aligned.
  // base float offset of row r  ==  r*VOCAB  ==  r (mod 4)
  const int head = (4 - (row & 3)) & 3;
  const int nv4  = (VOCAB - head) >> 2;
  const float4* __restrict__ x4 = (const float4*)(x + head);

  for (int i = tid; i < nv4; i += P1_THREADS) {
    float4 v = x4[i];
    os_update(s0, v.x);
    os_update(s1, v.y);
    os_update(s2, v.z);
    os_update(s3, v.w);
  }
  if (tid < head) os_update(s0, x[tid]);
  for (int i = head + 4 * nv4 + tid; i < VOCAB; i += P1_THREADS) os_update(s1, x[i]);

  os_merge(s0, s1); os_merge(s2, s3); os_merge(s0, s2);

  // wave64 butterfly
  for (int m = 1; m < 64; m <<= 1) {
    OS o;
    o.m1 = __shfl_xor(s0.m1, m);
    o.m2 = __shfl_xor(s0.m2, m);
    o.Z  = __shfl_xor(s0.Z,  m);
    o.S1 = __shfl_xor(s0.S1, m);
    os_merge(s0, o);
  }

  __shared__ OS sred[P1_THREADS / 64];
  const int lane = tid & 63, wid = tid >> 6;
  if (lane == 0) sred[wid] = s0;
  __syncthreads();

  if (tid == 0) {
    OS a = sred[0];
    for (int w = 1; w < P1_THREADS / 64; ++w) os_merge(a, sred[w]);
    float m       = a.m1;
    float lnZ     = logf(a.Z);
    float ptl     = m + lnZ - xt;            // -log_softmax[target]
    float entropy = lnZ - a.S1 / a.Z;
    float log_v   = logf((float)VOCAB);
    float cf      = 1.0f / a.Z;              // p_max = e^{m1-m1}/Z
    float margin  = (1.0f - __expf(a.m2 - m)) / a.Z;
    float dif     = (entropy / log_v + (1.0f - margin) + ptl / log_v) / 3.0f;
    diff[row] = dif;
    loss[row] = ptl;
    conf[row] = cf;
  }
}

__global__ __launch_bounds__(P2_THREADS) void cggr_finalize(
    const float* __restrict__ diff, const float* __restrict__ loss,
    const float* __restrict__ conf, const int* __restrict__ step_ptr,
    float* __restrict__ out)
{
  __shared__ float s[NTOK];          // 16 KiB sort buffer
  __shared__ float rl[P2_THREADS / 64];
  __shared__ float rc[P2_THREADS / 64];
  __shared__ int ks;

  const int tid  = threadIdx.x;
  const int lane = tid & 63, wid = tid >> 6;

  // ---- mean confidence ----
  float c = 0.0f;
  for (int i = tid; i < NTOK; i += P2_THREADS) c += conf[i];
  for (int m = 1; m < 64; m <<= 1) c += __shfl_xor(c, m);
  if (lane == 0) rl[wid] = c;
  __syncthreads();

  if (tid == 0) {
    float sum = 0.0f;
    for (int w = 0; w < P2_THREADS / 64; ++w) sum += rl[w];
    float mean_conf  = sum / (float)NTOK;
    float step       = (float)step_ptr[0];
    float progress   = fminf(1.0f, step / 1000.0f);     // WARMUP_STEPS=1000
    float base_ratio = 1.0f - progress * (1.0f - 0.25f); // MIN_TOKENS_RATIO=0.25
    float ratio      = base_ratio * (1.0f + 0.5f * (0.5f - mean_conf));
    ratio = fminf(fmaxf(ratio, 0.05f), 1.0f);
    int k = (int)rintf(ratio * (float)NTOK);   // rintf = round-half-even, matches jnp.round
    k = k < 1 ? 1 : (k > NTOK ? NTOK : k);
    ks = k;
  }

  // ---- load difficulties & bitonic sort (ascending) ----
  for (int i = tid; i < NTOK; i += P2_THREADS) s[i] = diff[i];
  __syncthreads();

  for (int size = 2; size <= NTOK; size <<= 1) {
    for (int stride = size >> 1; stride > 0; stride >>= 1) {
      for (int t = tid; t < NTOK / 2; t += P2_THREADS) {
        int i = 2 * t - (t & (stride - 1));
        int j = i + stride;
        bool up = ((i & size) == 0);
        float a = s[i], b = s[j];
        if ((a > b) == up) { s[i] = b; s[j] = a; }
      }
      __syncthreads();
    }
  }

  const float thresh = s[NTOK - ks];   // k-th largest

  // ---- masked loss ----
  float ls = 0.0f, cnt = 0.0f;
  for (int i = tid; i < NTOK; i += P2_THREADS) {
    float d = diff[i];
    if (d >= thresh) { ls += loss[i]; cnt += 1.0f; }
  }
  for (int m = 1; m < 64; m <<= 1) {
    ls  += __shfl_xor(ls, m);
    cnt += __shfl_xor(cnt, m);
  }
  if (lane == 0) { rl[wid] = ls; rc[wid] = cnt; }
  __syncthreads();
  if (tid == 0) {
    float tl = 0.0f, tc = 0.0f;
    for (int w = 0; w < P2_THREADS / 64; ++w) { tl += rl[w]; tc += rc[w]; }
    out[0] = tl / fmaxf(tc, 1.0f);
  }
}

extern "C" void kernel_launch(void* const* d_in, const int* in_sizes, int n_in,
                              void* d_out, int out_size, void* d_ws, size_t ws_size,
                              hipStream_t stream) {
  const float* logits  = (const float*)d_in[0];
  const int*   targets = (const int*)d_in[1];
  const int*   step    = (const int*)d_in[2];
  float* ws   = (float*)d_ws;
  float* diff = ws;
  float* loss = ws + NTOK;
  float* conf = ws + 2 * NTOK;

  hipLaunchKernelGGL(cggr_rowstats, dim3(NTOK), dim3(P1_THREADS), 0, stream,
                     logits, targets, diff, loss, conf);
  hipLaunchKernelGGL(cggr_finalize, dim3(1), dim3(P2_THREADS), 0, stream,
                     diff, loss, conf, step, (float*)d_out);
}

// Round 2
// 172.813 us; speedup vs baseline: 1.0896x; 1.0896x over previous
//
#include <hip/hip_runtime.h>

#define VOCAB 50257
#define NTOK 4096
#define P1_THREADS 256
#define P2_THREADS 1024
#define NEG_HUGE -3.402823466e+38f

// Online softmax state over a multiset:
//   m  = max, m2 = second max, Z = sum e^{x-m}, S1 = sum (x-m) e^{x-m}
struct OS { float m, m2, Z, S1; };

__device__ __forceinline__ void os_init(OS& s) {
  s.m = NEG_HUGE; s.m2 = NEG_HUGE; s.Z = 0.0f; s.S1 = 0.0f;
}

// Merge a local summary (ml, m2l, zl, s1l) into state a. One exp total.
__device__ __forceinline__ void os_merge(OS& a, float ml, float m2l, float zl, float s1l) {
  float M  = fmaxf(a.m, ml);
  float mn = fminf(a.m, ml);
  float m2 = fmaxf(fmaxf(a.m2, m2l), mn);
  float e  = __expf(mn - M);          // exp of the smaller-max shift; other side is e^0=1
  bool  om = a.m >= ml;
  float eo = om ? 1.0f : e;
  float en = om ? e : 1.0f;
  // (a.m - M) and (ml - M): exactly one is 0; NEG_HUGE is finite so (-3.4e38)*0 = 0 stays clean
  float S1 = eo * fmaf(a.m - M, a.Z, a.S1) + en * fmaf(ml - M, zl, s1l);
  float Z  = fmaf(eo, a.Z, en * zl);
  a.m = M; a.m2 = m2; a.Z = Z; a.S1 = S1;
}

// Batched update with 4 elements: local max/2nd-max/Z/S1, then one merge.
__device__ __forceinline__ void os_update4(OS& s, float4 v) {
  float a  = fmaxf(v.x, v.y), b = fminf(v.x, v.y);
  float c  = fmaxf(v.z, v.w), d = fminf(v.z, v.w);
  float ml  = fmaxf(a, c);
  float m2l = fmaxf(fminf(a, c), fmaxf(b, d));    // exact 2nd max of 4
  float d0 = v.x - ml, d1 = v.y - ml, d2 = v.z - ml, d3 = v.w - ml;
  float e0 = __expf(d0), e1 = __expf(d1), e2 = __expf(d2), e3 = __expf(d3);
  float zl  = (e0 + e1) + (e2 + e3);
  float s1l = fmaf(d0, e0, fmaf(d1, e1, fmaf(d2, e2, d3 * e3)));
  os_merge(s, ml, m2l, zl, s1l);
}

__global__ __launch_bounds__(P1_THREADS) void cggr_rowstats(
    const float* __restrict__ logits, const int* __restrict__ targets,
    float* __restrict__ diff, float* __restrict__ loss, float* __restrict__ conf)
{
  const int row = blockIdx.x;
  const float* __restrict__ x = logits + (size_t)row * VOCAB;
  const int tid = threadIdx.x;

  float xt = 0.0f;
  if (tid == 0) xt = x[targets[row]];

  // row base offset mod 4 == row mod 4 (VOCAB % 4 == 1): peel head for 16B alignment
  const int head = (4 - (row & 3)) & 3;
  const int nv4  = (VOCAB - head) >> 2;
  const float4* __restrict__ x4 = (const float4*)(x + head);

  OS s0, s1; os_init(s0); os_init(s1);

  int i = tid;
  for (; i + P1_THREADS < nv4; i += 2 * P1_THREADS) {
    float4 va = x4[i];
    float4 vb = x4[i + P1_THREADS];
    os_update4(s0, va);
    os_update4(s1, vb);
  }
  if (i < nv4) os_update4(s0, x4[i]);

  if (tid < head) os_merge(s1, x[tid], NEG_HUGE, 1.0f, 0.0f);
  for (int t = head + 4 * nv4 + tid; t < VOCAB; t += P1_THREADS)
    os_merge(s1, x[t], NEG_HUGE, 1.0f, 0.0f);

  os_merge(s0, s1.m, s1.m2, s1.Z, s1.S1);

  // wave64 butterfly
  for (int m = 1; m < 64; m <<= 1) {
    OS o;
    o.m  = __shfl_xor(s0.m,  m);
    o.m2 = __shfl_xor(s0.m2, m);
    o.Z  = __shfl_xor(s0.Z,  m);
    o.S1 = __shfl_xor(s0.S1, m);
    os_merge(s0, o.m, o.m2, o.Z, o.S1);
  }

  __shared__ OS sred[P1_THREADS / 64];
  const int lane = tid & 63, wid = tid >> 6;
  if (lane == 0) sred[wid] = s0;
  __syncthreads();

  if (tid == 0) {
    OS a = sred[0];
    for (int w = 1; w < P1_THREADS / 64; ++w)
      os_merge(a, sred[w].m, sred[w].m2, sred[w].Z, sred[w].S1);
    float m       = a.m;
    float lnZ     = logf(a.Z);
    float ptl     = m + lnZ - xt;            // -log_softmax[target]
    float entropy = lnZ - a.S1 / a.Z;
    float log_v   = logf((float)VOCAB);
    float cf      = 1.0f / a.Z;              // p_max
    float margin  = (1.0f - __expf(a.m2 - m)) / a.Z;
    float dif     = (entropy / log_v + (1.0f - margin) + ptl / log_v) / 3.0f;
    diff[row] = dif;
    loss[row] = ptl;
    conf[row] = cf;
  }
}

__global__ __launch_bounds__(P2_THREADS) void cggr_finalize(
    const float* __restrict__ diff, const float* __restrict__ loss,
    const float* __restrict__ conf, const int* __restrict__ step_ptr,
    float* __restrict__ out)
{
  __shared__ float redF[16];
  __shared__ int   redI[2][16];
  __shared__ float redL[16], redC[16];

  const int tid = threadIdx.x, lane = tid & 63, wid = tid >> 6;

  // Each thread owns 4 rows (strided, coalesced), kept in registers.
  float dv[4];
  unsigned u[4];
  float cs = 0.0f;
  #pragma unroll
  for (int j = 0; j < 4; ++j) {
    int i = tid + P2_THREADS * j;
    dv[j] = diff[i];
    cs   += conf[i];
    unsigned b = __float_as_uint(dv[j]);
    u[j] = b ^ ((b & 0x80000000u) ? 0xFFFFFFFFu : 0x80000000u);  // monotonic map
  }

  // ---- mean confidence -> k (computed redundantly by all threads) ----
  for (int m = 1; m < 64; m <<= 1) cs += __shfl_xor(cs, m);
  if (lane == 0) redF[wid] = cs;
  __syncthreads();
  float sum = 0.0f;
  #pragma unroll
  for (int w = 0; w < 16; ++w) sum += redF[w];
  float mean_conf  = sum / (float)NTOK;
  float step       = (float)step_ptr[0];
  float progress   = fminf(1.0f, step / 1000.0f);       // WARMUP_STEPS
  float base_ratio = 1.0f - progress * (1.0f - 0.25f);  // MIN_TOKENS_RATIO
  float ratio      = base_ratio * (1.0f + 0.5f * (0.5f - mean_conf));
  ratio = fminf(fmaxf(ratio, 0.05f), 1.0f);
  int k = (int)rintf(ratio * (float)NTOK);              // round-half-even = jnp.round
  k = k < 1 ? 1 : (k > NTOK ? NTOK : k);

  // ---- k-th largest via 32-round MSB binary search on monotonic keys ----
  // T = max{ v : #{u >= v} >= k }  (exact element value, ties handled)
  unsigned T = 0;
  int parity = 0;
  for (int bit = 31; bit >= 0; --bit) {
    unsigned cand = T | (1u << bit);
    int cnt = (u[0] >= cand) + (u[1] >= cand) + (u[2] >= cand) + (u[3] >= cand);
    for (int m = 1; m < 64; m <<= 1) cnt += __shfl_xor(cnt, m);
    if (lane == 0) redI[parity][wid] = cnt;
    __syncthreads();
    int tot = 0;
    #pragma unroll
    for (int w = 0; w < 16; ++w) tot += redI[parity][w];
    if (tot >= k) T = cand;       // all threads take identical branch
    parity ^= 1;
  }
  // inverse monotonic map -> float threshold (exactly an element value)
  unsigned tb = (T & 0x80000000u) ? (T ^ 0x80000000u) : ~T;
  float thresh = __uint_as_float(tb);

  // ---- masked loss (float compare, exactly like the reference mask) ----
  float ls = 0.0f, cn = 0.0f;
  #pragma unroll
  for (int j = 0; j < 4; ++j) {
    if (dv[j] >= thresh) { ls += loss[tid + P2_THREADS * j]; cn += 1.0f; }
  }
  for (int m = 1; m < 64; m <<= 1) {
    ls += __shfl_xor(ls, m);
    cn += __shfl_xor(cn, m);
  }
  if (lane == 0) { redL[wid] = ls; redC[wid] = cn; }
  __syncthreads();
  if (tid == 0) {
    float tl = 0.0f, tc = 0.0f;
    #pragma unroll
    for (int w = 0; w < 16; ++w) { tl += redL[w]; tc += redC[w]; }
    out[0] = tl / fmaxf(tc, 1.0f);
  }
}

extern "C" void kernel_launch(void* const* d_in, const int* in_sizes, int n_in,
                              void* d_out, int out_size, void* d_ws, size_t ws_size,
                              hipStream_t stream) {
  const float* logits  = (const float*)d_in[0];
  const int*   targets = (const int*)d_in[1];
  const int*   step    = (const int*)d_in[2];
  float* ws   = (float*)d_ws;
  float* diff = ws;
  float* loss = ws + NTOK;
  float* conf = ws + 2 * NTOK;

  hipLaunchKernelGGL(cggr_rowstats, dim3(NTOK), dim3(P1_THREADS), 0, stream,
                     logits, targets, diff, loss, conf);
  hipLaunchKernelGGL(cggr_finalize, dim3(1), dim3(P2_THREADS), 0, stream,
                     diff, loss, conf, step, (float*)d_out);
}

// Round 4
// 154.436 us; speedup vs baseline: 1.2192x; 1.1190x over previous
//
#include <hip/hip_runtime.h>

#define VOCAB 50257
#define NTOK 4096
#define P1_THREADS 256
#define P2_THREADS 1024
#define NEG_HUGE -3.402823466e+38f

typedef float floatx4 __attribute__((ext_vector_type(4)));

// Online softmax state over a multiset:
//   m  = max, m2 = second max, Z = sum e^{x-m}, S1 = sum (x-m) e^{x-m}
struct OS { float m, m2, Z, S1; };

__device__ __forceinline__ void os_init(OS& s) {
  s.m = NEG_HUGE; s.m2 = NEG_HUGE; s.Z = 0.0f; s.S1 = 0.0f;
}

// Merge a local summary (ml, m2l, zl, s1l) into state a. One exp total.
__device__ __forceinline__ void os_merge(OS& a, float ml, float m2l, float zl, float s1l) {
  float M  = fmaxf(a.m, ml);
  float mn = fminf(a.m, ml);
  float m2 = fmaxf(fmaxf(a.m2, m2l), mn);
  float e  = __expf(mn - M);          // exp of the smaller-max shift; other side is e^0=1
  bool  om = a.m >= ml;
  float eo = om ? 1.0f : e;
  float en = om ? e : 1.0f;
  float S1 = eo * fmaf(a.m - M, a.Z, a.S1) + en * fmaf(ml - M, zl, s1l);
  float Z  = fmaf(eo, a.Z, en * zl);
  a.m = M; a.m2 = m2; a.Z = Z; a.S1 = S1;
}

// Batched update with 4 elements: local max/2nd-max/Z/S1, then one merge.
__device__ __forceinline__ void os_update4(OS& s, floatx4 v) {
  float a  = fmaxf(v.x, v.y), b = fminf(v.x, v.y);
  float c  = fmaxf(v.z, v.w), d = fminf(v.z, v.w);
  float ml  = fmaxf(a, c);
  float m2l = fmaxf(fminf(a, c), fmaxf(b, d));    // exact 2nd max of 4
  float d0 = v.x - ml, d1 = v.y - ml, d2 = v.z - ml, d3 = v.w - ml;
  float e0 = __expf(d0), e1 = __expf(d1), e2 = __expf(d2), e3 = __expf(d3);
  float zl  = (e0 + e1) + (e2 + e3);
  float s1l = fmaf(d0, e0, fmaf(d1, e1, fmaf(d2, e2, d3 * e3)));
  os_merge(s, ml, m2l, zl, s1l);
}

__global__ __launch_bounds__(P1_THREADS) void cggr_rowstats(
    const float* __restrict__ logits, const int* __restrict__ targets,
    float* __restrict__ diff, float* __restrict__ loss, float* __restrict__ conf)
{
  const int row = blockIdx.x;
  const float* __restrict__ x = logits + (size_t)row * VOCAB;
  const int tid = threadIdx.x;

  float xt = 0.0f;
  if (tid == 0) xt = x[targets[row]];

  // row base offset mod 4 == row mod 4 (VOCAB % 4 == 1): peel head for 16B alignment
  const int head = (4 - (row & 3)) & 3;
  const int nv4  = (VOCAB - head) >> 2;
  const floatx4* __restrict__ x4 = (const floatx4*)(x + head);

  OS s0, s1, s2, s3;
  os_init(s0); os_init(s1); os_init(s2); os_init(s3);

  // 4 independent streams: 4 outstanding 16B loads per thread per iteration
  int i = tid;
  for (; i + 3 * P1_THREADS < nv4; i += 4 * P1_THREADS) {
    floatx4 va = __builtin_nontemporal_load(&x4[i]);
    floatx4 vb = __builtin_nontemporal_load(&x4[i +     P1_THREADS]);
    floatx4 vc = __builtin_nontemporal_load(&x4[i + 2 * P1_THREADS]);
    floatx4 vd = __builtin_nontemporal_load(&x4[i + 3 * P1_THREADS]);
    os_update4(s0, va);
    os_update4(s1, vb);
    os_update4(s2, vc);
    os_update4(s3, vd);
  }
  for (; i < nv4; i += P1_THREADS)
    os_update4(s0, __builtin_nontemporal_load(&x4[i]));

  if (tid < head) os_merge(s1, x[tid], NEG_HUGE, 1.0f, 0.0f);
  for (int t = head + 4 * nv4 + tid; t < VOCAB; t += P1_THREADS)
    os_merge(s1, x[t], NEG_HUGE, 1.0f, 0.0f);

  os_merge(s0, s1.m, s1.m2, s1.Z, s1.S1);
  os_merge(s2, s3.m, s3.m2, s3.Z, s3.S1);
  os_merge(s0, s2.m, s2.m2, s2.Z, s2.S1);

  // wave64 butterfly
  for (int m = 1; m < 64; m <<= 1) {
    OS o;
    o.m  = __shfl_xor(s0.m,  m);
    o.m2 = __shfl_xor(s0.m2, m);
    o.Z  = __shfl_xor(s0.Z,  m);
    o.S1 = __shfl_xor(s0.S1, m);
    os_merge(s0, o.m, o.m2, o.Z, o.S1);
  }

  __shared__ OS sred[P1_THREADS / 64];
  const int lane = tid & 63, wid = tid >> 6;
  if (lane == 0) sred[wid] = s0;
  __syncthreads();

  if (tid == 0) {
    OS a = sred[0];
    for (int w = 1; w < P1_THREADS / 64; ++w)
      os_merge(a, sred[w].m, sred[w].m2, sred[w].Z, sred[w].S1);
    float m       = a.m;
    float lnZ     = logf(a.Z);
    float ptl     = m + lnZ - xt;            // -log_softmax[target]
    float entropy = lnZ - a.S1 / a.Z;
    float log_v   = logf((float)VOCAB);
    float cf      = 1.0f / a.Z;              // p_max
    float margin  = (1.0f - __expf(a.m2 - m)) / a.Z;
    float dif     = (entropy / log_v + (1.0f - margin) + ptl / log_v) / 3.0f;
    diff[row] = dif;
    loss[row] = ptl;
    conf[row] = cf;
  }
}

__global__ __launch_bounds__(P2_THREADS) void cggr_finalize(
    const float* __restrict__ diff, const float* __restrict__ loss,
    const float* __restrict__ conf, const int* __restrict__ step_ptr,
    float* __restrict__ out)
{
  __shared__ float redF[16];
  __shared__ int   redI[2][16];
  __shared__ float redL[16], redC[16];

  const int tid = threadIdx.x, lane = tid & 63, wid = tid >> 6;

  // Each thread owns 4 rows (strided, coalesced), kept in registers.
  float dv[4];
  unsigned u[4];
  float cs = 0.0f;
  #pragma unroll
  for (int j = 0; j < 4; ++j) {
    int i = tid + P2_THREADS * j;
    dv[j] = diff[i];
    cs   += conf[i];
    unsigned b = __float_as_uint(dv[j]);
    u[j] = b ^ ((b & 0x80000000u) ? 0xFFFFFFFFu : 0x80000000u);  // monotonic map
  }

  // ---- mean confidence -> k (computed redundantly by all threads) ----
  for (int m = 1; m < 64; m <<= 1) cs += __shfl_xor(cs, m);
  if (lane == 0) redF[wid] = cs;
  __syncthreads();
  float sum = 0.0f;
  #pragma unroll
  for (int w = 0; w < 16; ++w) sum += redF[w];
  float mean_conf  = sum / (float)NTOK;
  float step       = (float)step_ptr[0];
  float progress   = fminf(1.0f, step / 1000.0f);       // WARMUP_STEPS
  float base_ratio = 1.0f - progress * (1.0f - 0.25f);  // MIN_TOKENS_RATIO
  float ratio      = base_ratio * (1.0f + 0.5f * (0.5f - mean_conf));
  ratio = fminf(fmaxf(ratio, 0.05f), 1.0f);
  int k = (int)rintf(ratio * (float)NTOK);              // round-half-even = jnp.round
  k = k < 1 ? 1 : (k > NTOK ? NTOK : k);

  // ---- k-th largest via 32-round MSB binary search on monotonic keys ----
  unsigned T = 0;
  int parity = 0;
  for (int bit = 31; bit >= 0; --bit) {
    unsigned cand = T | (1u << bit);
    int cnt = (u[0] >= cand) + (u[1] >= cand) + (u[2] >= cand) + (u[3] >= cand);
    for (int m = 1; m < 64; m <<= 1) cnt += __shfl_xor(cnt, m);
    if (lane == 0) redI[parity][wid] = cnt;
    __syncthreads();
    int tot = 0;
    #pragma unroll
    for (int w = 0; w < 16; ++w) tot += redI[parity][w];
    if (tot >= k) T = cand;       // all threads take identical branch
    parity ^= 1;
  }
  unsigned tb = (T & 0x80000000u) ? (T ^ 0x80000000u) : ~T;
  float thresh = __uint_as_float(tb);

  // ---- masked loss (float compare, exactly like the reference mask) ----
  float ls = 0.0f, cn = 0.0f;
  #pragma unroll
  for (int j = 0; j < 4; ++j) {
    if (dv[j] >= thresh) { ls += loss[tid + P2_THREADS * j]; cn += 1.0f; }
  }
  for (int m = 1; m < 64; m <<= 1) {
    ls += __shfl_xor(ls, m);
    cn += __shfl_xor(cn, m);
  }
  if (lane == 0) { redL[wid] = ls; redC[wid] = cn; }
  __syncthreads();
  if (tid == 0) {
    float tl = 0.0f, tc = 0.0f;
    #pragma unroll
    for (int w = 0; w < 16; ++w) { tl += redL[w]; tc += redC[w]; }
    out[0] = tl / fmaxf(tc, 1.0f);
  }
}

extern "C" void kernel_launch(void* const* d_in, const int* in_sizes, int n_in,
                              void* d_out, int out_size, void* d_ws, size_t ws_size,
                              hipStream_t stream) {
  const float* logits  = (const float*)d_in[0];
  const int*   targets = (const int*)d_in[1];
  const int*   step    = (const int*)d_in[2];
  float* ws   = (float*)d_ws;
  float* diff = ws;
  float* loss = ws + NTOK;
  float* conf = ws + 2 * NTOK;

  hipLaunchKernelGGL(cggr_rowstats, dim3(NTOK), dim3(P1_THREADS), 0, stream,
                     logits, targets, diff, loss, conf);
  hipLaunchKernelGGL(cggr_finalize, dim3(1), dim3(P2_THREADS), 0, stream,
                     diff, loss, conf, step, (float*)d_out);
}